// Round 7
// baseline (1107.434 us; speedup 1.0000x reference)
//
#include <hip/hip_runtime.h>
#include <hip/hip_bf16.h>
#include <stdint.h>

// Problem constants (fixed by reference)
#define H_K   2048
#define VV    128256
#define NROWS 1024
#define SOFTCAP_F   30.0f
#define LS_EPS      0.1f
#define ZLOSS_SCALE 1e-4f
#define IGNORE_IDX  (-100)

// 256x256 tile, BK=64, 8 waves (2M x 4N), wave owns 128x64.
// MFMA: mfma_scale_f32_32x32x64_f8f6f4 (e4m3 x e4m3), unit scales (E8M0=127).
#define BM 256
#define BN 256
#define BK 64
#define NKT 32
#define THREADS 512

typedef __attribute__((ext_vector_type(4)))  int   i32x4;
typedef __attribute__((ext_vector_type(8)))  int   i32x8;
typedef __attribute__((ext_vector_type(16))) float f32x16;

__device__ __forceinline__ void gload_lds16(const void* g, void* l) {
    __builtin_amdgcn_global_load_lds(
        (const __attribute__((address_space(1))) unsigned*)g,
        (__attribute__((address_space(3))) unsigned*)l, 16, 0, 0);
}
#define WAITVM(N) asm volatile("s_waitcnt vmcnt(" #N ")" ::: "memory")
#define WAITLG_SB do { asm volatile("s_waitcnt lgkmcnt(0)" ::: "memory"); \
                       __builtin_amdgcn_sched_barrier(0); } while (0)

// v_cvt_pk_fp8_f32: packs fp8(a),fp8(b) into 16 bits of old (imm word sel)
template <bool HI>
__device__ __forceinline__ unsigned pk8(float a, float b, unsigned old) {
    return (unsigned)__builtin_amdgcn_cvt_pk_fp8_f32(a, b, (int)old, HI);
}
// fragment = 32 fp8 bytes split as two 16B slots 1024B apart (h-slot LDS layout)
__device__ __forceinline__ i32x8 ldfrag(const char* p) {
    i32x4 lo = *(const i32x4*)p;
    i32x4 hi = *(const i32x4*)(p + 1024);
    return __builtin_shufflevector(lo, hi, 0, 1, 2, 3, 4, 5, 6, 7);
}

// ---------------- x fp32 -> fp8 in MFMA-fragment-major layout ----------------
// panel (row>>5, k>>6) = 2048B: [h0 slot 1024B][h1 slot 1024B], slot byte =
// lane*16 where lane l = ((k>>5)&1)<<5 | (row&31). GEMM stages A with LINEAR
// gload_lds (panel image) and reads frags at lane*16 / +1024 (conflict-free).
__global__ void cvt_x_fp8(const float* __restrict__ x, char* __restrict__ xh) {
    int f = blockIdx.x * 256 + threadIdx.x;          // 65536 fragments
    int row = f >> 6, k32 = f & 63;                  // 32-elem k-chunk
    const char* src = (const char*)x + (size_t)row * 8192 + k32 * 128;
    unsigned d[8];
    #pragma unroll
    for (int i = 0; i < 8; ++i) {
        float4 v = *(const float4*)(src + i * 16);
        unsigned u = pk8<false>(v.x, v.y, 0u);
        d[i] = pk8<true>(v.z, v.w, u);
    }
    char* dst = xh + (size_t)((row >> 5) * 32 + (k32 >> 1)) * 2048
                   + ((((k32 & 1) << 5) | (row & 31))) * 16;
    uint4 u0; u0.x = d[0]; u0.y = d[1]; u0.z = d[2]; u0.w = d[3];
    uint4 u1; u1.x = d[4]; u1.y = d[5]; u1.z = d[6]; u1.w = d[7];
    *(uint4*)dst          = u0;    // k 0..15  (h=0 slot)
    *(uint4*)(dst + 1024) = u1;    // k 16..31 (h=1 slot)
}

// ---------------- fused GEMM + softcap + partial reductions ----------------
// Per iter (BK=64): 2 phases x {frag ds_reads | stage | barrier | lgkm0 |
// 4 MFMA | barrier}. Counted vmcnt: ph1 vmcnt(2) releases this iter's 8 W
// loads for cvt; end vmcnt(8) releases the 2 A-DMAs. Never drains W prefetch.
__global__ __launch_bounds__(THREADS, 2)
void gemm_fused(const float* __restrict__ W,
                const char* __restrict__ xh,
                const int* __restrict__ y,
                float* __restrict__ ws_se,
                float* __restrict__ ws_sl,
                float* __restrict__ ws_zy)
{
    __shared__ char As[2][16384];   // 8 m-panels x 2KB, dbuf
    __shared__ char Bs[2][16384];   // 8 n-panels x 2KB, dbuf

    const int tid  = threadIdx.x;
    const int lane = tid & 63;
    const int wid  = tid >> 6;
    const int wm   = wid >> 2;          // 0..1 -> 128 rows
    const int wn   = wid & 3;           // 0..3 -> 64 cols

    // bijective XCD swizzle: nwg = 2004 = 8*250+4 (m204)
    const int bid  = blockIdx.x;
    const int xcd  = bid & 7, o8 = bid >> 3;
    const int work = (xcd < 4 ? xcd * 251 : 1004 + (xcd - 4) * 250) + o8;
    const int mblk = work & 3;
    const int nblk = work >> 2;
    const int row0 = mblk * BM;
    const int col0 = nblk * BN;

    // A staging: 2 gload_lds (8KB apart in m) per iter; LINEAR panel copy.
    // wave pair (wid>>1) covers one panel: wid&1 selects the 1024B h-slot.
    const char* a_src = xh + (size_t)(mblk * 8 + (tid >> 7)) * 65536
                           + ((tid >> 6) & 1) * 1024 + (tid & 63) * 16;
    // W: thread covers col c=tid>>1, k-half kh=tid&1 -> 32 fp32 = 128B = one frag
    const char* w_src = (const char*)W + (size_t)(col0 + (tid >> 1)) * 8192
                                       + (tid & 1) * 128;
    // B frag write: panel np=tid>>6 (32 cols), lane l=(kh<<5)|(c&31)
    const int b_w = (tid >> 6) * 2048 + ((((tid & 1) << 5) | ((tid >> 1) & 31))) * 16;

    // MFMA frag read offsets (panel*2048 + lane*16; +1024 = h=1 slot)
    const int aoff = wm * 4 * 2048 + lane * 16;   // + mi*2048
    const int boff = wn * 2 * 2048 + lane * 16;   // + ni*2048

    f32x16 acc[4][2] = {};
    float4 wv[8];

    // ---- prologue: W(0)+A(0) staged; wv reloaded with W(1); drain A ----
    {
        #pragma unroll
        for (int i = 0; i < 8; ++i) wv[i] = *(const float4*)(w_src + i * 16);
        gload_lds16(a_src,          (char*)As + wid * 1024);
        gload_lds16(a_src + 262144, (char*)As + 8192 + wid * 1024);
        WAITVM(2);                       // 8 W(0) done; 2 A-DMA in flight
        unsigned d0 = pk8<false>(wv[0].x, wv[0].y, 0u); d0 = pk8<true>(wv[0].z, wv[0].w, d0);
        unsigned d1 = pk8<false>(wv[1].x, wv[1].y, 0u); d1 = pk8<true>(wv[1].z, wv[1].w, d1);
        unsigned d2 = pk8<false>(wv[2].x, wv[2].y, 0u); d2 = pk8<true>(wv[2].z, wv[2].w, d2);
        unsigned d3 = pk8<false>(wv[3].x, wv[3].y, 0u); d3 = pk8<true>(wv[3].z, wv[3].w, d3);
        unsigned d4 = pk8<false>(wv[4].x, wv[4].y, 0u); d4 = pk8<true>(wv[4].z, wv[4].w, d4);
        unsigned d5 = pk8<false>(wv[5].x, wv[5].y, 0u); d5 = pk8<true>(wv[5].z, wv[5].w, d5);
        unsigned d6 = pk8<false>(wv[6].x, wv[6].y, 0u); d6 = pk8<true>(wv[6].z, wv[6].w, d6);
        unsigned d7 = pk8<false>(wv[7].x, wv[7].y, 0u); d7 = pk8<true>(wv[7].z, wv[7].w, d7);
        uint4 u0; u0.x = d0; u0.y = d1; u0.z = d2; u0.w = d3;
        uint4 u1; u1.x = d4; u1.y = d5; u1.z = d6; u1.w = d7;
        *(uint4*)((char*)Bs + b_w)        = u0;
        *(uint4*)((char*)Bs + b_w + 1024) = u1;
        #pragma unroll
        for (int i = 0; i < 8; ++i) wv[i] = *(const float4*)(w_src + 256 + i * 16);
        WAITVM(8);                       // A(0) landed; W(1) stays in flight
        asm volatile("s_waitcnt lgkmcnt(0)" ::: "memory");
        __builtin_amdgcn_s_barrier();
    }

#define MFMS(D, AV, BV) D = __builtin_amdgcn_mfma_scale_f32_32x32x64_f8f6f4( \
                            AV, BV, D, 0, 0, 0, 127, 0, 127)

#define ITER(J, CUR, ISSA, ISSW, DOCVT, VME) do { \
    const char* Ab_ = (const char*)As + (CUR) * 16384; \
    const char* Bb_ = (const char*)Bs + (CUR) * 16384; \
    /* -------- phase 0: mi 0,1 -------- */ \
    i32x8 b0_ = ldfrag(Bb_ + boff); \
    i32x8 b1_ = ldfrag(Bb_ + boff + 2048); \
    i32x8 a0_ = ldfrag(Ab_ + aoff); \
    i32x8 a1_ = ldfrag(Ab_ + aoff + 2048); \
    if (ISSA) { \
        gload_lds16(a_src +          (size_t)((J) + 1) * 2048, \
                    (char*)As + ((CUR) ^ 1) * 16384 + wid * 1024); \
        gload_lds16(a_src + 262144 + (size_t)((J) + 1) * 2048, \
                    (char*)As + ((CUR) ^ 1) * 16384 + 8192 + wid * 1024); \
    } \
    __builtin_amdgcn_s_barrier(); \
    WAITLG_SB; \
    __builtin_amdgcn_s_setprio(1); \
    MFMS(acc[0][0], a0_, b0_); MFMS(acc[0][1], a0_, b1_); \
    MFMS(acc[1][0], a1_, b0_); MFMS(acc[1][1], a1_, b1_); \
    __builtin_amdgcn_s_setprio(0); \
    __builtin_amdgcn_s_barrier(); \
    /* -------- phase 1: mi 2,3 -------- */ \
    a0_ = ldfrag(Ab_ + aoff + 4096); \
    a1_ = ldfrag(Ab_ + aoff + 6144); \
    WAITVM(2); /* W(J+1) regs ready; A-DMA(J+1) stays */ \
    if (DOCVT) { \
        char* Bn_ = (char*)Bs + ((CUR) ^ 1) * 16384; \
        unsigned e0 = pk8<false>(wv[0].x, wv[0].y, 0u); e0 = pk8<true>(wv[0].z, wv[0].w, e0); \
        unsigned e1 = pk8<false>(wv[1].x, wv[1].y, 0u); e1 = pk8<true>(wv[1].z, wv[1].w, e1); \
        unsigned e2 = pk8<false>(wv[2].x, wv[2].y, 0u); e2 = pk8<true>(wv[2].z, wv[2].w, e2); \
        unsigned e3 = pk8<false>(wv[3].x, wv[3].y, 0u); e3 = pk8<true>(wv[3].z, wv[3].w, e3); \
        unsigned e4 = pk8<false>(wv[4].x, wv[4].y, 0u); e4 = pk8<true>(wv[4].z, wv[4].w, e4); \
        unsigned e5 = pk8<false>(wv[5].x, wv[5].y, 0u); e5 = pk8<true>(wv[5].z, wv[5].w, e5); \
        unsigned e6 = pk8<false>(wv[6].x, wv[6].y, 0u); e6 = pk8<true>(wv[6].z, wv[6].w, e6); \
        unsigned e7 = pk8<false>(wv[7].x, wv[7].y, 0u); e7 = pk8<true>(wv[7].z, wv[7].w, e7); \
        uint4 u0_; u0_.x = e0; u0_.y = e1; u0_.z = e2; u0_.w = e3; \
        uint4 u1_; u1_.x = e4; u1_.y = e5; u1_.z = e6; u1_.w = e7; \
        *(uint4*)(Bn_ + b_w)        = u0_; \
        *(uint4*)(Bn_ + b_w + 1024) = u1_; \
    } \
    if (ISSW) { \
        wv[0] = *(const float4*)(w_src + (size_t)((J) + 2) * 256); \
        wv[1] = *(const float4*)(w_src + (size_t)((J) + 2) * 256 + 16); \
        wv[2] = *(const float4*)(w_src + (size_t)((J) + 2) * 256 + 32); \
        wv[3] = *(const float4*)(w_src + (size_t)((J) + 2) * 256 + 48); \
        wv[4] = *(const float4*)(w_src + (size_t)((J) + 2) * 256 + 64); \
        wv[5] = *(const float4*)(w_src + (size_t)((J) + 2) * 256 + 80); \
        wv[6] = *(const float4*)(w_src + (size_t)((J) + 2) * 256 + 96); \
        wv[7] = *(const float4*)(w_src + (size_t)((J) + 2) * 256 + 112); \
    } \
    __builtin_amdgcn_s_barrier(); \
    WAITLG_SB; \
    __builtin_amdgcn_s_setprio(1); \
    MFMS(acc[2][0], a0_, b0_); MFMS(acc[2][1], a0_, b1_); \
    MFMS(acc[3][0], a1_, b0_); MFMS(acc[3][1], a1_, b1_); \
    __builtin_amdgcn_s_setprio(0); \
    WAITVM(VME); /* A-DMA(J+1) landed before buffer swap */ \
    __builtin_amdgcn_s_barrier(); \
} while (0)

    #pragma unroll 1
    for (int j2 = 0; j2 < 15; ++j2) {
        ITER(2 * j2,     0, 1, 1, 1, 8);
        ITER(2 * j2 + 1, 1, 1, 1, 1, 8);
    }
    ITER(30, 0, 1, 0, 1, 0);    // last cvt (B31), no new W
    ITER(31, 1, 0, 0, 0, 0);    // compute only

    // ---- epilogue: softcap, z_y scatter, per-row partial sumexp/sumlogit ----
    // 32x32 C/D (m74/m101): col = lane&31, row = (e&3) + 8*(e>>2) + 4*(lane>>5)
    #pragma unroll
    for (int mi = 0; mi < 4; ++mi)
        #pragma unroll
        for (int ni = 0; ni < 2; ++ni)
            #pragma unroll
            for (int e = 0; e < 16; ++e) {
                float v  = acc[mi][ni][e];
                float ex = __expf(v * (1.0f / 15.0f));            // e^{2v/30}
                acc[mi][ni][e] = SOFTCAP_F - 60.0f / (ex + 1.0f); // 30*tanh(v/30)
            }

    const int h  = lane >> 5;
    const int cl = lane & 31;
    const int cbase = col0 + wn * 64;
    #pragma unroll
    for (int mi = 0; mi < 4; ++mi) {
        #pragma unroll
        for (int e = 0; e < 16; ++e) {
            const int rit  = (e & 3) + ((e >> 2) << 3) + (h << 2);
            const int grow = row0 + wm * 128 + mi * 32 + rit;
            int ty = y[grow];
            int tc = ty - cbase;
            if ((unsigned)tc < 64u && (tc & 31) == cl)
                ws_zy[grow] = (tc >> 5) ? acc[mi][1][e] : acc[mi][0][e];
            float v0 = acc[mi][0][e], v1 = acc[mi][1][e];
            float sl_ = v0 + v1;
            float se_ = __expf(v0) + __expf(v1);   // |logits|<=30, no max-shift
            #pragma unroll
            for (int d = 1; d < 32; d <<= 1) {     // reduce across the 32 cols
                se_ += __shfl_xor(se_, d, 64);
                sl_ += __shfl_xor(sl_, d, 64);
            }
            if (cl == 0) {
                atomicAdd(&ws_se[grow], se_);
                atomicAdd(&ws_sl[grow], sl_);
            }
        }
    }
}

// ---------------- finalize: per-token loss + mean ----------------
__global__ void finalize_kernel(const float* __restrict__ ws_se,
                                const float* __restrict__ ws_sl,
                                const float* __restrict__ ws_zy,
                                const int* __restrict__ y,
                                float* __restrict__ out, int n)
{
    __shared__ float sL[16], sC[16];
    const int tid = threadIdx.x;
    float loss = 0.f, cnt = 0.f;
    if (tid < n) {
        int ty = y[tid];
        if (ty != IGNORE_IDX) {
            float lse = logf(ws_se[tid]);
            float ce  = lse - (1.0f - LS_EPS) * ws_zy[tid]
                          - (LS_EPS / (float)VV) * ws_sl[tid];
            loss = ce + ZLOSS_SCALE * lse * lse;
            cnt  = 1.f;
        }
    }
    #pragma unroll
    for (int d = 32; d >= 1; d >>= 1) {
        loss += __shfl_down(loss, d, 64);
        cnt  += __shfl_down(cnt,  d, 64);
    }
    const int w = tid >> 6;
    if ((tid & 63) == 0) { sL[w] = loss; sC[w] = cnt; }
    __syncthreads();
    if (tid == 0) {
        float L = 0.f, C = 0.f;
        #pragma unroll
        for (int i = 0; i < 16; ++i) { L += sL[i]; C += sC[i]; }
        out[0] = L / fmaxf(C, 1.0f);
    }
}

extern "C" void kernel_launch(void* const* d_in, const int* in_sizes, int n_in,
                              void* d_out, int out_size, void* d_ws, size_t ws_size,
                              hipStream_t stream) {
    const float* x = (const float*)d_in[0];
    const float* W = (const float*)d_in[1];
    const int*   y = (const int*)d_in[2];
    float* out = (float*)d_out;

    char*  ws    = (char*)d_ws;
    float* ws_se = (float*)(ws);            // [1024] sumexp
    float* ws_sl = (float*)(ws + 4096);     // [1024] sumlogit
    float* ws_zy = (float*)(ws + 8192);     // [1024] target logit
    char*  xh    = ws + 16384;              // [1024*2048] fp8 x, fragment-major

    (void)hipMemsetAsync(ws, 0, 12288, stream);

    cvt_x_fp8<<<256, 256, 0, stream>>>(x, xh);

    int grid = (VV / BN) * (NROWS / BM);    // 501 * 4 = 2004
    gemm_fused<<<grid, THREADS, 0, stream>>>(W, xh, y, ws_se, ws_sl, ws_zy);

    finalize_kernel<<<1, 1024, 0, stream>>>(ws_se, ws_sl, ws_zy, y, out, NROWS);
}

// Round 8
// 1001.286 us; speedup vs baseline: 1.1060x; 1.1060x over previous
//
#include <hip/hip_runtime.h>
#include <hip/hip_bf16.h>
#include <stdint.h>

// Problem constants (fixed by reference)
#define H_K   2048
#define VV    128256
#define NROWS 1024
#define NCB   501            // vocab col-blocks of 256
#define SOFTCAP_F   30.0f
#define LS_EPS      0.1f
#define ZLOSS_SCALE 1e-4f
#define IGNORE_IDX  (-100)

typedef __attribute__((ext_vector_type(4)))  int   i32x4;
typedef __attribute__((ext_vector_type(8)))  int   i32x8;
typedef __attribute__((ext_vector_type(16))) float f32x16;

__device__ __forceinline__ void gload_lds16(const void* g, void* l) {
    __builtin_amdgcn_global_load_lds(
        (const __attribute__((address_space(1))) unsigned*)g,
        (__attribute__((address_space(3))) unsigned*)l, 16, 0, 0);
}
#define WAITVM(N) asm volatile("s_waitcnt vmcnt(" #N ")" ::: "memory")
#define WAITLG_SB do { asm volatile("s_waitcnt lgkmcnt(0)" ::: "memory"); \
                       __builtin_amdgcn_sched_barrier(0); } while (0)

template <bool HI>
__device__ __forceinline__ unsigned pk8(float a, float b, unsigned old) {
    return (unsigned)__builtin_amdgcn_cvt_pk_fp8_f32(a, b, (int)old, HI);
}
// fragment = 32 fp8 k-bytes as two 16B slots 1024B apart (h-slot panel layout)
__device__ __forceinline__ i32x8 ldfrag(const char* p) {
    i32x4 lo = *(const i32x4*)p;
    i32x4 hi = *(const i32x4*)(p + 1024);
    return __builtin_shufflevector(lo, hi, 0, 1, 2, 3, 4, 5, 6, 7);
}

// ---- fp32 -> fp8 fragment-major panels (shared by x and W) ----
// panel (row>>5, k>>6) = 2048B: [h0 1024B][h1 1024B], slot byte = l*16,
// lane l = ((k>>5)&1)<<5 | (row&31). Panel index = (row>>5)*32 + (k>>6).
// Coalesced 128B reads; 16B scattered writes L2-merge (4 writers/64B sector
// are threads t,t+64,t+128,t+192 of the same block).
__device__ __forceinline__ void cvt_frag_row(const char* src, char* dst_base,
                                             int row, int k32) {
    unsigned d[8];
    #pragma unroll
    for (int i = 0; i < 8; ++i) {
        float4 v = *(const float4*)(src + i * 16);
        unsigned u = pk8<false>(v.x, v.y, 0u);
        d[i] = pk8<true>(v.z, v.w, u);
    }
    char* dst = dst_base + (size_t)((row >> 5) * 32 + (k32 >> 1)) * 2048
                         + ((((k32 & 1) << 5) | (row & 31))) * 16;
    uint4 u0; u0.x = d[0]; u0.y = d[1]; u0.z = d[2]; u0.w = d[3];
    uint4 u1; u1.x = d[4]; u1.y = d[5]; u1.z = d[6]; u1.w = d[7];
    *(uint4*)dst          = u0;    // k 0..15  (h=0)
    *(uint4*)(dst + 1024) = u1;    // k 16..31 (h=1)
}

__global__ void cvt_x_fp8(const float* __restrict__ x, char* __restrict__ xh) {
    int f = blockIdx.x * 256 + threadIdx.x;          // 65536 fragments
    int row = f >> 6, k32 = f & 63;
    cvt_frag_row((const char*)x + (size_t)row * 8192 + k32 * 128, xh, row, k32);
}

__global__ void cvt_w_fp8(const float* __restrict__ W, char* __restrict__ Wh,
                          int col0) {
    int f = blockIdx.x * 256 + threadIdx.x;          // nb*16384 fragments
    int row = f >> 6, k32 = f & 63;                  // row = chunk-local col
    cvt_frag_row((const char*)W + (size_t)(col0 + row) * 8192 + k32 * 128,
                 Wh, row, k32);
}

// ---------------- fused GEMM + softcap + partial reductions ----------------
// 128x256 tile, 4 waves (1M x 4N), wave owns 128x64, acc[4][2] f32x16.
// All staging via global_load_lds (A 2 + B 4 calls/wave/iter). ONE barrier/iter:
// {12 ds_read_b128 | 6 gload_lds(t+1) | lgkm0 | 8 MFMA | vmcnt(0) | barrier}.
__global__ __launch_bounds__(256, 2)
void gemm_fused(const char* __restrict__ Wh,    // chunk-local frag-major fp8
                const char* __restrict__ xh,
                const int* __restrict__ y,
                float* __restrict__ ws_se,
                float* __restrict__ ws_sl,
                float* __restrict__ ws_zy,
                int col_base, int qx)           // qx = works per XCD = nb
{
    __shared__ char As[2][8192];    // 4 m-panels x 2KB, dbuf
    __shared__ char Bs[2][16384];   // 8 n-panels x 2KB, dbuf  (48 KB total)

    const int tid  = threadIdx.x;
    const int lane = tid & 63;
    const int wid  = tid >> 6;           // 0..3 = wave col group

    // XCD-grouped work order: grid = 8*qx, m-sharers consecutive per XCD
    const int bid  = blockIdx.x;
    const int work = (bid & 7) * qx + (bid >> 3);
    const int mblk = work & 7;           // 8 m-sharers of a W col-tile adjacent
    const int nblk = work >> 3;
    const int row0 = mblk * 128;

    // staging sources (frag-major linear; DMA dest = uniform base + lane*16)
    const char* aP  = xh + (size_t)(mblk * 4 + wid) * 65536 + lane * 16;
    const char* bP0 = Wh + (size_t)(nblk * 8 + 2 * wid) * 65536 + lane * 16;
    const char* bP1 = bP0 + 65536;

    const int aoff = lane * 16;                  // + mi*2048
    const int boff = 2 * wid * 2048 + lane * 16; // + ni*2048

    f32x16 acc[4][2] = {};

    // ---- prologue: stage K-step 0 into buf0 ----
    {
        char* aD  = (char*)As + wid * 2048;
        char* bD0 = (char*)Bs + 2 * wid * 2048;
        gload_lds16(aP,         aD);        gload_lds16(aP + 1024,  aD + 1024);
        gload_lds16(bP0,        bD0);       gload_lds16(bP0 + 1024, bD0 + 1024);
        gload_lds16(bP1,        bD0 + 2048); gload_lds16(bP1 + 1024, bD0 + 3072);
        WAITVM(0);
        __builtin_amdgcn_s_barrier();
    }

#define MFMS(D, AV, BV) D = __builtin_amdgcn_mfma_scale_f32_32x32x64_f8f6f4( \
                            AV, BV, D, 0, 0, 0, 127, 0, 127)

    #pragma unroll 1
    for (int j = 0; j < 32; ++j) {
        const int cur = j & 1;
        const char* Ab = (const char*)As + cur * 8192;
        const char* Bb = (const char*)Bs + cur * 16384;
        i32x8 b0 = ldfrag(Bb + boff);
        i32x8 b1 = ldfrag(Bb + boff + 2048);
        i32x8 a0 = ldfrag(Ab + aoff);
        i32x8 a1 = ldfrag(Ab + aoff + 2048);
        i32x8 a2 = ldfrag(Ab + aoff + 4096);
        i32x8 a3 = ldfrag(Ab + aoff + 6144);
        if (j < 31) {
            const size_t ko = (size_t)(j + 1) * 2048;
            char* aDn = (char*)As + (cur ^ 1) * 8192  + wid * 2048;
            char* bDn = (char*)Bs + (cur ^ 1) * 16384 + 2 * wid * 2048;
            gload_lds16(aP + ko,         aDn);        gload_lds16(aP + ko + 1024,  aDn + 1024);
            gload_lds16(bP0 + ko,        bDn);        gload_lds16(bP0 + ko + 1024, bDn + 1024);
            gload_lds16(bP1 + ko,        bDn + 2048); gload_lds16(bP1 + ko + 1024, bDn + 3072);
        }
        WAITLG_SB;
        __builtin_amdgcn_s_setprio(1);
        MFMS(acc[0][0], a0, b0); MFMS(acc[0][1], a0, b1);
        MFMS(acc[1][0], a1, b0); MFMS(acc[1][1], a1, b1);
        MFMS(acc[2][0], a2, b0); MFMS(acc[2][1], a2, b1);
        MFMS(acc[3][0], a3, b0); MFMS(acc[3][1], a3, b1);
        __builtin_amdgcn_s_setprio(0);
        WAITVM(0);                       // DMA(t+1) landed in every wave
        __builtin_amdgcn_s_barrier();
    }

    // ---- epilogue: softcap, z_y scatter, per-row partial sumexp/sumlogit ----
    // 32x32 C/D (m74/m101, R7-verified): col = lane&31,
    // row = (e&3) + 8*(e>>2) + 4*(lane>>5)
    #pragma unroll
    for (int mi = 0; mi < 4; ++mi)
        #pragma unroll
        for (int ni = 0; ni < 2; ++ni)
            #pragma unroll
            for (int e = 0; e < 16; ++e) {
                float v  = acc[mi][ni][e];
                float ex = __expf(v * (1.0f / 15.0f));            // e^{2v/30}
                acc[mi][ni][e] = SOFTCAP_F - 60.0f / (ex + 1.0f); // 30*tanh(v/30)
            }

    const int h  = lane >> 5;
    const int cl = lane & 31;
    const int cbase = col_base + nblk * 256 + wid * 64;
    #pragma unroll
    for (int mi = 0; mi < 4; ++mi) {
        #pragma unroll
        for (int e = 0; e < 16; ++e) {
            const int rit  = (e & 3) + ((e >> 2) << 3) + (h << 2);
            const int grow = row0 + mi * 32 + rit;
            int ty = y[grow];
            int tc = ty - cbase;
            if ((unsigned)tc < 64u && (tc & 31) == cl)
                ws_zy[grow] = (tc >> 5) ? acc[mi][1][e] : acc[mi][0][e];
            float v0 = acc[mi][0][e], v1 = acc[mi][1][e];
            float sl_ = v0 + v1;
            float se_ = __expf(v0) + __expf(v1);   // |logits|<=30, no max-shift
            #pragma unroll
            for (int d = 1; d < 32; d <<= 1) {     // reduce across 32 cols
                se_ += __shfl_xor(se_, d, 64);
                sl_ += __shfl_xor(sl_, d, 64);
            }
            if (cl == 0) {
                atomicAdd(&ws_se[grow], se_);
                atomicAdd(&ws_sl[grow], sl_);
            }
        }
    }
}

// ---------------- finalize: per-token loss + mean ----------------
__global__ void finalize_kernel(const float* __restrict__ ws_se,
                                const float* __restrict__ ws_sl,
                                const float* __restrict__ ws_zy,
                                const int* __restrict__ y,
                                float* __restrict__ out, int n)
{
    __shared__ float sL[16], sC[16];
    const int tid = threadIdx.x;
    float loss = 0.f, cnt = 0.f;
    if (tid < n) {
        int ty = y[tid];
        if (ty != IGNORE_IDX) {
            float lse = logf(ws_se[tid]);
            float ce  = lse - (1.0f - LS_EPS) * ws_zy[tid]
                          - (LS_EPS / (float)VV) * ws_sl[tid];
            loss = ce + ZLOSS_SCALE * lse * lse;
            cnt  = 1.f;
        }
    }
    #pragma unroll
    for (int d = 32; d >= 1; d >>= 1) {
        loss += __shfl_down(loss, d, 64);
        cnt  += __shfl_down(cnt,  d, 64);
    }
    const int w = tid >> 6;
    if ((tid & 63) == 0) { sL[w] = loss; sC[w] = cnt; }
    __syncthreads();
    if (tid == 0) {
        float L = 0.f, C = 0.f;
        #pragma unroll
        for (int i = 0; i < 16; ++i) { L += sL[i]; C += sC[i]; }
        out[0] = L / fmaxf(C, 1.0f);
    }
}

extern "C" void kernel_launch(void* const* d_in, const int* in_sizes, int n_in,
                              void* d_out, int out_size, void* d_ws, size_t ws_size,
                              hipStream_t stream) {
    const float* x = (const float*)d_in[0];
    const float* W = (const float*)d_in[1];
    const int*   y = (const int*)d_in[2];
    float* out = (float*)d_out;

    char*  ws    = (char*)d_ws;
    float* ws_se = (float*)(ws);              // [1024] sumexp
    float* ws_sl = (float*)(ws + 4096);       // [1024] sumlogit
    float* ws_zy = (float*)(ws + 8192);       // [1024] target logit
    char*  xh    = ws + 16384;                // 2 MB fp8 x, frag-major
    char*  Wh    = ws + 16384 + 2097152;      // fp8 W chunk, frag-major

    // chunk vocab by available ws (deterministic: ws_size fixed per run)
    const size_t fixed = 16384 + 2097152;
    const size_t avail = ws_size > fixed ? ws_size - fixed : 0;
    int nbc = (int)(avail / 524288);          // 512 KB per 256-col block
    if (nbc > NCB) nbc = NCB;
    if (nbc < 1)   nbc = 1;

    (void)hipMemsetAsync(ws, 0, 12288, stream);
    cvt_x_fp8<<<256, 256, 0, stream>>>(x, xh);

    for (int c0 = 0; c0 < NCB; c0 += nbc) {
        const int nb = (NCB - c0 < nbc) ? (NCB - c0) : nbc;
        cvt_w_fp8<<<nb * 64, 256, 0, stream>>>(W, Wh, c0 * 256);
        gemm_fused<<<nb * 8, 256, 0, stream>>>(Wh, xh, y, ws_se, ws_sl, ws_zy,
                                               c0 * 256, nb);
    }

    finalize_kernel<<<1, 1024, 0, stream>>>(ws_se, ws_sl, ws_zy, y, out, NROWS);
}

// Round 9
// 952.224 us; speedup vs baseline: 1.1630x; 1.0515x over previous
//
#include <hip/hip_runtime.h>
#include <hip/hip_bf16.h>
#include <stdint.h>

// Problem constants (fixed by reference)
#define H_K   2048
#define VV    128256
#define NROWS 1024
#define NCB   501            // vocab col-blocks of 256
#define SOFTCAP_F   30.0f
#define LS_EPS      0.1f
#define ZLOSS_SCALE 1e-4f
#define IGNORE_IDX  (-100)

typedef __attribute__((ext_vector_type(4)))  int   i32x4;
typedef __attribute__((ext_vector_type(8)))  int   i32x8;
typedef __attribute__((ext_vector_type(16))) float f32x16;

__device__ __forceinline__ void gload_lds16(const void* g, void* l) {
    __builtin_amdgcn_global_load_lds(
        (const __attribute__((address_space(1))) unsigned*)g,
        (__attribute__((address_space(3))) unsigned*)l, 16, 0, 0);
}
#define WAITVM(N) asm volatile("s_waitcnt vmcnt(" #N ")" ::: "memory")
#define WAITLG_SB do { asm volatile("s_waitcnt lgkmcnt(0)" ::: "memory"); \
                       __builtin_amdgcn_sched_barrier(0); } while (0)

template <bool HI>
__device__ __forceinline__ unsigned pk8(float a, float b, unsigned old) {
    return (unsigned)__builtin_amdgcn_cvt_pk_fp8_f32(a, b, (int)old, HI);
}
// fragment = 32 fp8 k-bytes as two 16B slots 1024B apart (h-slot panel layout)
__device__ __forceinline__ i32x8 ldfrag(const char* p) {
    i32x4 lo = *(const i32x4*)p;
    i32x4 hi = *(const i32x4*)(p + 1024);
    return __builtin_shufflevector(lo, hi, 0, 1, 2, 3, 4, 5, 6, 7);
}

// ---- fp32 -> fp8 fragment-major panels (layout identical to R8) ----
// panel (row>>5, k>>6) = 2048B: [h0 1024B][h1 1024B], slot byte = l*16,
// lane l = ((k32&1)<<5) | (row&31).
// v3 thread map: t -> (row = t&31, k32 = q*8 + (t>>5)); within each 64-thread
// group lane == t&63, so piece0/piece1 stores are CONTIGUOUS 1KB per group.
__device__ __forceinline__ void cvt_frag_row(const char* src, char* dst_base,
                                             int row, int k32) {
    unsigned d[8];
    #pragma unroll
    for (int i = 0; i < 8; ++i) {
        float4 v = *(const float4*)(src + i * 16);
        unsigned u = pk8<false>(v.x, v.y, 0u);
        d[i] = pk8<true>(v.z, v.w, u);
    }
    char* dst = dst_base + (size_t)((row >> 5) * 32 + (k32 >> 1)) * 2048
                         + ((((k32 & 1) << 5) | (row & 31))) * 16;
    uint4 u0; u0.x = d[0]; u0.y = d[1]; u0.z = d[2]; u0.w = d[3];
    uint4 u1; u1.x = d[4]; u1.y = d[5]; u1.z = d[6]; u1.w = d[7];
    *(uint4*)dst          = u0;    // k 0..15  (h=0)
    *(uint4*)(dst + 1024) = u1;    // k 16..31 (h=1)
}

__global__ void cvt_x_fp8(const float* __restrict__ x, char* __restrict__ xh) {
    const int g = blockIdx.x >> 3, q = blockIdx.x & 7;   // 32 row-groups x 8 slabs
    const int t = threadIdx.x;
    const int row = g * 32 + (t & 31);
    const int k32 = q * 8 + (t >> 5);
    cvt_frag_row((const char*)x + (size_t)row * 8192 + (size_t)k32 * 128,
                 xh, row, k32);
}

__global__ void cvt_w_fp8(const float* __restrict__ W, char* __restrict__ Wh,
                          int col0) {
    const int g = blockIdx.x >> 3, q = blockIdx.x & 7;   // nb*8 row-groups x 8
    const int t = threadIdx.x;
    const int row = g * 32 + (t & 31);                   // chunk-local col
    const int k32 = q * 8 + (t >> 5);
    cvt_frag_row((const char*)W + (size_t)(col0 + row) * 8192 + (size_t)k32 * 128,
                 Wh, row, k32);
}

// ---------------- fused GEMM + softcap + partial reductions ----------------
// 128x256 tile, 4 waves (1M x 4N), wave owns 128x64, acc[4][2] f32x16.
// TRIPLE-buffered LDS (72KB, 2 blocks/CU) + counted vmcnt (T3+T4):
// iter j: {12 ds_read(buf j%3) | issue 6 DMA(j+2 -> buf (j+2)%3) | lgkm0 |
// 8 MFMA | vmcnt(6) [drains DMA(j+1), issued a FULL iter ago] | barrier}.
// Never drains to 0 until the tail.
__global__ __launch_bounds__(256, 2)
void gemm_fused(const char* __restrict__ Wh,    // chunk-local frag-major fp8
                const char* __restrict__ xh,
                const int* __restrict__ y,
                float* __restrict__ ws_se,
                float* __restrict__ ws_sl,
                float* __restrict__ ws_zy,
                int col_base, int qx)           // qx = works per XCD = nb
{
    __shared__ char As[3][8192];    // 4 m-panels x 2KB, 3-buf
    __shared__ char Bs[3][16384];   // 8 n-panels x 2KB, 3-buf  (72 KB)

    const int tid  = threadIdx.x;
    const int lane = tid & 63;
    const int wid  = tid >> 6;           // 0..3 = wave col group

    // XCD-grouped work order: grid = 8*qx, m-sharers consecutive per XCD
    const int bid  = blockIdx.x;
    const int work = (bid & 7) * qx + (bid >> 3);
    const int mblk = work & 7;           // 8 m-sharers of a W col-tile adjacent
    const int nblk = work >> 3;
    const int row0 = mblk * 128;

    // staging sources (frag-major linear; DMA dest = uniform base + lane*16)
    const char* aP  = xh + (size_t)(mblk * 4 + wid) * 65536 + lane * 16;
    const char* bP0 = Wh + (size_t)(nblk * 8 + 2 * wid) * 65536 + lane * 16;
    const char* bP1 = bP0 + 65536;

    const int aoff = lane * 16;                  // + mi*2048
    const int boff = 2 * wid * 2048 + lane * 16; // + ni*2048

    f32x16 acc[4][2] = {};

#define STAGE(KO, BUFI) do { \
    char* aD_ = (char*)As + (BUFI) * 8192  + wid * 2048; \
    char* bD_ = (char*)Bs + (BUFI) * 16384 + 2 * wid * 2048; \
    gload_lds16(aP  + (KO),        aD_);        gload_lds16(aP  + (KO) + 1024, aD_ + 1024); \
    gload_lds16(bP0 + (KO),        bD_);        gload_lds16(bP0 + (KO) + 1024, bD_ + 1024); \
    gload_lds16(bP1 + (KO),        bD_ + 2048); gload_lds16(bP1 + (KO) + 1024, bD_ + 3072); \
} while (0)

#define MFMS(D, AV, BV) D = __builtin_amdgcn_mfma_scale_f32_32x32x64_f8f6f4( \
                            AV, BV, D, 0, 0, 0, 127, 0, 127)

#define PHASE(CUR) do { \
    const char* Ab_ = (const char*)As + (CUR) * 8192; \
    const char* Bb_ = (const char*)Bs + (CUR) * 16384; \
    i32x8 b0_ = ldfrag(Bb_ + boff); \
    i32x8 b1_ = ldfrag(Bb_ + boff + 2048); \
    i32x8 a0_ = ldfrag(Ab_ + aoff); \
    i32x8 a1_ = ldfrag(Ab_ + aoff + 2048); \
    i32x8 a2_ = ldfrag(Ab_ + aoff + 4096); \
    i32x8 a3_ = ldfrag(Ab_ + aoff + 6144); \
    WAITLG_SB; \
    __builtin_amdgcn_s_setprio(1); \
    MFMS(acc[0][0], a0_, b0_); MFMS(acc[0][1], a0_, b1_); \
    MFMS(acc[1][0], a1_, b0_); MFMS(acc[1][1], a1_, b1_); \
    MFMS(acc[2][0], a2_, b0_); MFMS(acc[2][1], a2_, b1_); \
    MFMS(acc[3][0], a3_, b0_); MFMS(acc[3][1], a3_, b1_); \
    __builtin_amdgcn_s_setprio(0); \
} while (0)

    // ---- prologue: stage K-steps 0 and 1; drain step 0 only ----
    STAGE(0,    0);
    STAGE(2048, 1);
    WAITVM(6);                   // buf0 landed; buf1's 6 still in flight
    __builtin_amdgcn_s_barrier();

    int cur = 0;
    #pragma unroll 1
    for (int j = 0; j < 30; ++j) {
        const int pre = (cur >= 1) ? cur - 1 : 2;     // (cur+2)%3
        // issue DMA(j+2) first (longest latency), then read frags of j
        STAGE((size_t)(j + 2) * 2048, pre);
        PHASE(cur);
        WAITVM(6);               // DMA(j+1) landed in every wave; (j+2) stays
        __builtin_amdgcn_s_barrier();
        cur = (cur >= 2) ? 0 : cur + 1;
    }
    // j=30 (cur==0): no new issue; drain DMA(31)
    PHASE(0);
    WAITVM(0);
    __builtin_amdgcn_s_barrier();
    // j=31 (buf1): compute only
    PHASE(1);

    // ---- epilogue: softcap, z_y scatter, per-row partial sumexp/sumlogit ----
    // 32x32 C/D (m74/m101, R7/R8-verified): col = lane&31,
    // row = (e&3) + 8*(e>>2) + 4*(lane>>5)
    #pragma unroll
    for (int mi = 0; mi < 4; ++mi)
        #pragma unroll
        for (int ni = 0; ni < 2; ++ni)
            #pragma unroll
            for (int e = 0; e < 16; ++e) {
                float v  = acc[mi][ni][e];
                float ex = __expf(v * (1.0f / 15.0f));            // e^{2v/30}
                acc[mi][ni][e] = SOFTCAP_F - 60.0f / (ex + 1.0f); // 30*tanh(v/30)
            }

    const int h  = lane >> 5;
    const int cl = lane & 31;
    const int cbase = col_base + nblk * 256 + wid * 64;
    #pragma unroll
    for (int mi = 0; mi < 4; ++mi) {
        #pragma unroll
        for (int e = 0; e < 16; ++e) {
            const int rit  = (e & 3) + ((e >> 2) << 3) + (h << 2);
            const int grow = row0 + mi * 32 + rit;
            int ty = y[grow];
            int tc = ty - cbase;
            if ((unsigned)tc < 64u && (tc & 31) == cl)
                ws_zy[grow] = (tc >> 5) ? acc[mi][1][e] : acc[mi][0][e];
            float v0 = acc[mi][0][e], v1 = acc[mi][1][e];
            float sl_ = v0 + v1;
            float se_ = __expf(v0) + __expf(v1);   // |logits|<=30, no max-shift
            #pragma unroll
            for (int d = 1; d < 32; d <<= 1) {     // reduce across 32 cols
                se_ += __shfl_xor(se_, d, 64);
                sl_ += __shfl_xor(sl_, d, 64);
            }
            if (cl == 0) {
                atomicAdd(&ws_se[grow], se_);
                atomicAdd(&ws_sl[grow], sl_);
            }
        }
    }
}

// ---------------- finalize: per-token loss + mean ----------------
__global__ void finalize_kernel(const float* __restrict__ ws_se,
                                const float* __restrict__ ws_sl,
                                const float* __restrict__ ws_zy,
                                const int* __restrict__ y,
                                float* __restrict__ out, int n)
{
    __shared__ float sL[16], sC[16];
    const int tid = threadIdx.x;
    float loss = 0.f, cnt = 0.f;
    if (tid < n) {
        int ty = y[tid];
        if (ty != IGNORE_IDX) {
            float lse = logf(ws_se[tid]);
            float ce  = lse - (1.0f - LS_EPS) * ws_zy[tid]
                          - (LS_EPS / (float)VV) * ws_sl[tid];
            loss = ce + ZLOSS_SCALE * lse * lse;
            cnt  = 1.f;
        }
    }
    #pragma unroll
    for (int d = 32; d >= 1; d >>= 1) {
        loss += __shfl_down(loss, d, 64);
        cnt  += __shfl_down(cnt,  d, 64);
    }
    const int w = tid >> 6;
    if ((tid & 63) == 0) { sL[w] = loss; sC[w] = cnt; }
    __syncthreads();
    if (tid == 0) {
        float L = 0.f, C = 0.f;
        #pragma unroll
        for (int i = 0; i < 16; ++i) { L += sL[i]; C += sC[i]; }
        out[0] = L / fmaxf(C, 1.0f);
    }
}

extern "C" void kernel_launch(void* const* d_in, const int* in_sizes, int n_in,
                              void* d_out, int out_size, void* d_ws, size_t ws_size,
                              hipStream_t stream) {
    const float* x = (const float*)d_in[0];
    const float* W = (const float*)d_in[1];
    const int*   y = (const int*)d_in[2];
    float* out = (float*)d_out;

    char*  ws    = (char*)d_ws;
    float* ws_se = (float*)(ws);              // [1024] sumexp
    float* ws_sl = (float*)(ws + 4096);       // [1024] sumlogit
    float* ws_zy = (float*)(ws + 8192);       // [1024] target logit
    char*  xh    = ws + 16384;                // 2 MB fp8 x, frag-major
    char*  Wh    = ws + 16384 + 2097152;      // fp8 W chunk, frag-major

    // chunk vocab by available ws (deterministic: ws_size fixed per run)
    const size_t fixed = 16384 + 2097152;
    const size_t avail = ws_size > fixed ? ws_size - fixed : 0;
    int nbc = (int)(avail / 524288);          // 512 KB per 256-col block
    if (nbc > NCB) nbc = NCB;
    if (nbc < 1)   nbc = 1;

    (void)hipMemsetAsync(ws, 0, 12288, stream);
    cvt_x_fp8<<<256, 256, 0, stream>>>(x, xh);

    for (int c0 = 0; c0 < NCB; c0 += nbc) {
        const int nb = (NCB - c0 < nbc) ? (NCB - c0) : nbc;
        cvt_w_fp8<<<nb * 64, 256, 0, stream>>>(W, Wh, c0 * 256);
        gemm_fused<<<nb * 8, 256, 0, stream>>>(Wh, xh, y, ws_se, ws_sl, ws_zy,
                                               c0 * 256, nb);
    }

    finalize_kernel<<<1, 1024, 0, stream>>>(ws_se, ws_sl, ws_zy, y, out, NROWS);
}